// Round 6
// baseline (163.035 us; speedup 1.0000x reference)
//
#include <hip/hip_runtime.h>

#define D_TOT 10000
#define ROWB  40000            // bytes per V table row (D_TOT*4)
#define NLEV  256
#define NPIX  131072           // 32*64*64
#define DPAD  10016            // padded D for partials (313*32)
#define NCHUNK 313             // ceil(10000/32) 32-d chunks
#define TROW  128              // bytes per level row in LDS tile (32 d * 4B)

__device__ __forceinline__ float4 fma4(const float4 a, const float4 b, const float4 c) {
  float4 r;
  r.x = fmaf(a.x, b.x, c.x);
  r.y = fmaf(a.y, b.y, c.y);
  r.z = fmaf(a.z, b.z, c.z);
  r.w = fmaf(a.w, b.w, c.w);
  return r;
}

// image levels (int32) -> packed LDS byte offset with XOR-swizzle bits:
// oo = (l<<7) | ((l&7)<<4). Bits 4-6 carry the row's bank rotation; bits 7+
// the row base. Final per-lane addr = oo ^ (dsub<<4)  (one v_xor, no add).
__global__ void prep_kernel(const int* __restrict__ img, int* __restrict__ idxoff) {
  int p = blockIdx.x * 256 + threadIdx.x;
  if (p < NPIX) {
    int l = img[p];
    idxoff[p] = (l << 7) | ((l & 7) << 4);
  }
}

// Each block: one 32-d chunk x one ROWS-row strip, all 32 images.
// 256 threads = 8 d-subgroups (4 d each, float4) x 32 image slots.
// Level row l is stored with its 16B slots XOR-permuted by (l&7) so that the
// two random rows co-issued in one LDS phase start at different banks
// (128-B rows all bank-0-aligned was the round-4 conflict source, 1.5e7 cyc).
template<int ROWS>
__global__ __launch_bounds__(256, 5)
void encode_kernel(const float* __restrict__ V, const float* __restrict__ X,
                   const float* __restrict__ Y, const int* __restrict__ idxoff,
                   float* __restrict__ part) {
  __shared__ float4 vlds[NLEV * 8];    // 32 KB: [level][8 x float4 = 32 d], slots swizzled
  const int tid   = threadIdx.x;
  const int chunk = blockIdx.x;
  const int q     = blockIdx.y;

  // ---- stage V tile: 256 levels x this block's 32 d's (swizzled slots) ----
  {
    const int seg = tid & 7;           // logical 16B segment within the 128B tile row
    const int l0  = tid >> 3;          // 0..31
    const int pseg = seg ^ (l0 & 7);   // physical slot (l&7 == l0&7 since stride 32)
    int off = chunk * TROW + seg * 16; // byte offset into a V row
    if (off + 16 > ROWB) off = ROWB - 16;   // clamp for partial last chunk (values unused)
    const char* Vb = (const char*)V;
#pragma unroll
    for (int k = 0; k < 8; ++k) {
      const int l = k * 32 + l0;
      vlds[l * 8 + pseg] = *(const float4*)(Vb + (size_t)l * ROWB + off);
    }
  }
  __syncthreads();

  const int dsub = tid & 7;
  const int b    = tid >> 3;           // image slot 0..31
  const int dsubB = dsub << 4;         // XOR'd into packed offsets per gather
  const char* ldsb = (const char*)vlds;
  const int d4  = chunk * 32 + dsub * 4;
  const int d4c = d4 > (D_TOT - 4) ? (D_TOT - 4) : d4;   // clamped for x/y loads (lanes past D discarded)
  const int ybase = q * ROWS;

  float4 rowacc[ROWS];
#pragma unroll
  for (int y = 0; y < ROWS; ++y) rowacc[y] = make_float4(0.f, 0.f, 0.f, 0.f);
  const int* iptr = idxoff + b * 4096 + ybase * 64;

#pragma unroll 1
  for (int wt = 0; wt < 8; ++wt) {
    // hoist x fragments for this 8-wide w tile (registers, reused over ROWS rows)
    float4 xt[8];
#pragma unroll
    for (int w = 0; w < 8; ++w)
      xt[w] = *(const float4*)(X + (size_t)(wt * 8 + w) * D_TOT + d4c);
#pragma unroll
    for (int y = 0; y < ROWS; ++y) {
      const int* ip = iptr + y * 64 + wt * 8;
      const int4 o0 = *(const int4*)ip;
      const int4 o1 = *(const int4*)(ip + 4);
      float4 v;
      v = *(const float4*)(ldsb + (o0.x ^ dsubB)); rowacc[y] = fma4(xt[0], v, rowacc[y]);
      v = *(const float4*)(ldsb + (o0.y ^ dsubB)); rowacc[y] = fma4(xt[1], v, rowacc[y]);
      v = *(const float4*)(ldsb + (o0.z ^ dsubB)); rowacc[y] = fma4(xt[2], v, rowacc[y]);
      v = *(const float4*)(ldsb + (o0.w ^ dsubB)); rowacc[y] = fma4(xt[3], v, rowacc[y]);
      v = *(const float4*)(ldsb + (o1.x ^ dsubB)); rowacc[y] = fma4(xt[4], v, rowacc[y]);
      v = *(const float4*)(ldsb + (o1.y ^ dsubB)); rowacc[y] = fma4(xt[5], v, rowacc[y]);
      v = *(const float4*)(ldsb + (o1.z ^ dsubB)); rowacc[y] = fma4(xt[6], v, rowacc[y]);
      v = *(const float4*)(ldsb + (o1.w ^ dsubB)); rowacc[y] = fma4(xt[7], v, rowacc[y]);
    }
  }

  // apply y binding in ascending row order, then store partial for this strip
  float4 acc = make_float4(0.f, 0.f, 0.f, 0.f);
#pragma unroll
  for (int y = 0; y < ROWS; ++y) {
    const float4 yv = *(const float4*)(Y + (size_t)(ybase + y) * D_TOT + d4c);
    acc = fma4(yv, rowacc[y], acc);
  }
  *(float4*)(part + (size_t)(q * 32 + b) * DPAD + d4) = acc;
}

__global__ void finalize_kernel(const float* __restrict__ part, float* __restrict__ out, int R) {
  const int d = blockIdx.x * 256 + threadIdx.x;
  const int b = blockIdx.y;
  if (d >= D_TOT) return;
  float s = 0.f;
  for (int r = 0; r < R; ++r) s += part[(size_t)(r * 32 + b) * DPAD + d];
  out[(size_t)b * D_TOT + d] = s > 0.f ? 1.0f : -1.0f;
}

extern "C" void kernel_launch(void* const* d_in, const int* in_sizes, int n_in,
                              void* d_out, int out_size, void* d_ws, size_t ws_size,
                              hipStream_t stream) {
  const float* V = (const float*)d_in[0];   // [256][10000]
  const float* X = (const float*)d_in[1];   // [64][10000]
  const float* Y = (const float*)d_in[2];   // [64][10000]
  const int*  img = (const int*)d_in[3];    // [32][1][64][64] levels
  float* out = (float*)d_out;               // [32][10000]

  int* idxoff = (int*)d_ws;
  const size_t base = 524288;               // 131072 * 4
  float* part = (float*)((char*)d_ws + base);

  const size_t per_strip = (size_t)32 * DPAD * 4;
  int R;
  if      (ws_size >= base + 16 * per_strip) R = 16;
  else if (ws_size >= base +  8 * per_strip) R = 8;
  else                                       R = 4;

  prep_kernel<<<dim3(512), dim3(256), 0, stream>>>(img, idxoff);
  if (R == 16)
    encode_kernel<4><<<dim3(NCHUNK, 16), dim3(256), 0, stream>>>(V, X, Y, idxoff, part);
  else if (R == 8)
    encode_kernel<8><<<dim3(NCHUNK, 8), dim3(256), 0, stream>>>(V, X, Y, idxoff, part);
  else
    encode_kernel<16><<<dim3(NCHUNK, 4), dim3(256), 0, stream>>>(V, X, Y, idxoff, part);
  finalize_kernel<<<dim3(40, 32), dim3(256), 0, stream>>>(part, out, R);
}

// Round 7
// 105.159 us; speedup vs baseline: 1.5504x; 1.5504x over previous
//
#include <hip/hip_runtime.h>

#define D_TOT 10000
#define ROWB  40000            // bytes per V table row (D_TOT*4)
#define NLEV  256
#define NPIX  131072           // 32*64*64
#define DPAD  10016            // padded D for partials (313*32)
#define NCHUNK 313             // ceil(10000/32) 32-d chunks
#define TROW  128              // bytes per level row in LDS tile (32 d * 4B)

__device__ __forceinline__ float4 fma4(const float4 a, const float4 b, const float4 c) {
  float4 r;
  r.x = fmaf(a.x, b.x, c.x);
  r.y = fmaf(a.y, b.y, c.y);
  r.z = fmaf(a.z, b.z, c.z);
  r.w = fmaf(a.w, b.w, c.w);
  return r;
}

// image levels (int32) -> pre-shifted LDS byte offsets (level * 128B tile row)
__global__ void prep_kernel(const int* __restrict__ img, int* __restrict__ idxoff) {
  int p = blockIdx.x * 256 + threadIdx.x;
  if (p < NPIX) idxoff[p] = img[p] << 7;
}

// Round-4 configuration (measured 104.7 us encode = 96% of the ds_read_b128
// instruction-rate floor: 5.12M wave-b128 / 256 CU x 12 cyc = 100.3 us).
// Linear 128-B level rows in LDS: 8-lane-contiguous runs; measured conflict
// tax ~6%. XOR swizzle (round 6) RAISED conflicts (breaks address-merge);
// global-gather offload (round 5) blew L1/L2 (FETCH 110->282 MB). Keep pure.
template<int ROWS>
__global__ __launch_bounds__(256, 4)
void encode_kernel(const float* __restrict__ V, const float* __restrict__ X,
                   const float* __restrict__ Y, const int* __restrict__ idxoff,
                   float* __restrict__ part) {
  __shared__ float4 vlds[NLEV * 8];    // 32 KB: [level][8 x float4 = 32 d]
  const int tid   = threadIdx.x;
  const int chunk = blockIdx.x;
  const int q     = blockIdx.y;

  // ---- stage V tile: 256 levels x this block's 32 d's ----
  {
    const int seg = tid & 7;           // 16B segment within the 128B tile row
    const int l0  = tid >> 3;          // 0..31
    int off = chunk * TROW + seg * 16; // byte offset into a V row
    if (off + 16 > ROWB) off = ROWB - 16;   // clamp for partial last chunk (values unused)
    const char* Vb = (const char*)V;
#pragma unroll
    for (int k = 0; k < 8; ++k) {
      const int l = k * 32 + l0;
      vlds[l * 8 + seg] = *(const float4*)(Vb + (size_t)l * ROWB + off);
    }
  }
  __syncthreads();

  const int dsub = tid & 7;
  const int b    = tid >> 3;           // image slot 0..31
  const char* vbase = (const char*)vlds + dsub * 16;
  const int d4  = chunk * 32 + dsub * 4;
  const int d4c = d4 > (D_TOT - 4) ? (D_TOT - 4) : d4;   // clamped for x/y loads (lanes past D discarded)
  const int ybase = q * ROWS;

  float4 rowacc[ROWS];
#pragma unroll
  for (int y = 0; y < ROWS; ++y) rowacc[y] = make_float4(0.f, 0.f, 0.f, 0.f);
  const int* iptr = idxoff + b * 4096 + ybase * 64;

#pragma unroll 1
  for (int wt = 0; wt < 8; ++wt) {
    // hoist x fragments for this 8-wide w tile (registers, reused over ROWS rows)
    float4 xt[8];
#pragma unroll
    for (int w = 0; w < 8; ++w)
      xt[w] = *(const float4*)(X + (size_t)(wt * 8 + w) * D_TOT + d4c);
#pragma unroll
    for (int y = 0; y < ROWS; ++y) {
      const int* ip = iptr + y * 64 + wt * 8;
      const int4 o0 = *(const int4*)ip;
      const int4 o1 = *(const int4*)(ip + 4);
      float4 v;
      v = *(const float4*)(vbase + o0.x); rowacc[y] = fma4(xt[0], v, rowacc[y]);
      v = *(const float4*)(vbase + o0.y); rowacc[y] = fma4(xt[1], v, rowacc[y]);
      v = *(const float4*)(vbase + o0.z); rowacc[y] = fma4(xt[2], v, rowacc[y]);
      v = *(const float4*)(vbase + o0.w); rowacc[y] = fma4(xt[3], v, rowacc[y]);
      v = *(const float4*)(vbase + o1.x); rowacc[y] = fma4(xt[4], v, rowacc[y]);
      v = *(const float4*)(vbase + o1.y); rowacc[y] = fma4(xt[5], v, rowacc[y]);
      v = *(const float4*)(vbase + o1.z); rowacc[y] = fma4(xt[6], v, rowacc[y]);
      v = *(const float4*)(vbase + o1.w); rowacc[y] = fma4(xt[7], v, rowacc[y]);
    }
  }

  // apply y binding in ascending row order, then store partial for this strip
  float4 acc = make_float4(0.f, 0.f, 0.f, 0.f);
#pragma unroll
  for (int y = 0; y < ROWS; ++y) {
    const float4 yv = *(const float4*)(Y + (size_t)(ybase + y) * D_TOT + d4c);
    acc = fma4(yv, rowacc[y], acc);
  }
  *(float4*)(part + (size_t)(q * 32 + b) * DPAD + d4) = acc;
}

// float4-vectorized finalize: sum strips in ascending r (matches reference
// y-scan order), then sign. D_TOT % 4 == 0 so full float4 coverage.
__global__ void finalize_kernel(const float* __restrict__ part, float* __restrict__ out, int R) {
  const int d4 = (blockIdx.x * 256 + threadIdx.x) * 4;
  const int b  = blockIdx.y;
  if (d4 >= D_TOT) return;
  float4 s = make_float4(0.f, 0.f, 0.f, 0.f);
  for (int r = 0; r < R; ++r) {
    const float4 p = *(const float4*)(part + (size_t)(r * 32 + b) * DPAD + d4);
    s.x += p.x; s.y += p.y; s.z += p.z; s.w += p.w;
  }
  float4 o;
  o.x = s.x > 0.f ? 1.0f : -1.0f;
  o.y = s.y > 0.f ? 1.0f : -1.0f;
  o.z = s.z > 0.f ? 1.0f : -1.0f;
  o.w = s.w > 0.f ? 1.0f : -1.0f;
  *(float4*)(out + (size_t)b * D_TOT + d4) = o;
}

extern "C" void kernel_launch(void* const* d_in, const int* in_sizes, int n_in,
                              void* d_out, int out_size, void* d_ws, size_t ws_size,
                              hipStream_t stream) {
  const float* V = (const float*)d_in[0];   // [256][10000]
  const float* X = (const float*)d_in[1];   // [64][10000]
  const float* Y = (const float*)d_in[2];   // [64][10000]
  const int*  img = (const int*)d_in[3];    // [32][1][64][64] levels
  float* out = (float*)d_out;               // [32][10000]

  int* idxoff = (int*)d_ws;
  const size_t base = 524288;               // 131072 * 4
  float* part = (float*)((char*)d_ws + base);

  const size_t per_strip = (size_t)32 * DPAD * 4;
  int R;
  if      (ws_size >= base + 16 * per_strip) R = 16;
  else if (ws_size >= base +  8 * per_strip) R = 8;
  else                                       R = 4;

  prep_kernel<<<dim3(512), dim3(256), 0, stream>>>(img, idxoff);
  if (R == 16)
    encode_kernel<4><<<dim3(NCHUNK, 16), dim3(256), 0, stream>>>(V, X, Y, idxoff, part);
  else if (R == 8)
    encode_kernel<8><<<dim3(NCHUNK, 8), dim3(256), 0, stream>>>(V, X, Y, idxoff, part);
  else
    encode_kernel<16><<<dim3(NCHUNK, 4), dim3(256), 0, stream>>>(V, X, Y, idxoff, part);
  finalize_kernel<<<dim3(10, 32), dim3(256), 0, stream>>>(part, out, R);
}